// Round 1
// baseline (45.781 us; speedup 1.0000x reference)
//
#include <hip/hip_runtime.h>

// CR gate, D=2, L=24, control=axis0, target=axis1.
// N = 2^24 amplitudes. R = 2^22 (size of the "rest" axis).
// out = stack([real, imag]) of U @ x, laid out as [N reals][N imags].
//
// control=0 half: identity copy.
// control=1 half: M1 = cos(a/2) I - i sin(a/2) X applied across target axis.

#define NELEM   (1u << 24)   // N
#define R_ELEM  (1u << 22)   // R = N / 4
#define R4      (1u << 20)   // R / 4 (float4 units)
#define COPY4   (1u << 21)   // (N/2)/4 float4 units in the copy half
#define TOTAL4  (COPY4 + R4) // total float4 work units

__global__ __launch_bounds__(256) void cr_gate_kernel(
    const float4* __restrict__ xr,
    const float4* __restrict__ xi,
    const float*  __restrict__ angle,
    float4* __restrict__ outr,
    float4* __restrict__ outi)
{
    const float half_a = 0.5f * angle[0];
    float s, c;
    sincosf(half_a, &s, &c);

    const unsigned stride = gridDim.x * blockDim.x;
    for (unsigned i = blockIdx.x * blockDim.x + threadIdx.x; i < TOTAL4; i += stride) {
        if (i < COPY4) {
            // control = 0: identity. Elements [0, N/2) of both arrays.
            outr[i] = xr[i];
            outi[i] = xi[i];
        } else {
            // control = 1: rotate target pair (t=0 at 2R + r, t=1 at 3R + r).
            const unsigned j  = i - COPY4;       // r / 4
            const unsigned ia = 2u * R4 + j;     // (2R + r) / 4
            const unsigned ib = 3u * R4 + j;     // (3R + r) / 4

            float4 r0 = xr[ia];
            float4 i0 = xi[ia];
            float4 r1 = xr[ib];
            float4 i1 = xi[ib];

            float4 or0, oi0, or1, oi1;
            const float* pr0 = (const float*)&r0;
            const float* pi0 = (const float*)&i0;
            const float* pr1 = (const float*)&r1;
            const float* pi1 = (const float*)&i1;
            float* por0 = (float*)&or0;
            float* poi0 = (float*)&oi0;
            float* por1 = (float*)&or1;
            float* poi1 = (float*)&oi1;

            #pragma unroll
            for (int k = 0; k < 4; ++k) {
                // out0 = c*x0 - i s * x1 ; out1 = -i s * x0 + c*x1
                por0[k] = c * pr0[k] + s * pi1[k];
                poi0[k] = c * pi0[k] - s * pr1[k];
                por1[k] = c * pr1[k] + s * pi0[k];
                poi1[k] = c * pi1[k] - s * pr0[k];
            }

            outr[ia] = or0;
            outi[ia] = oi0;
            outr[ib] = or1;
            outi[ib] = oi1;
        }
    }
}

extern "C" void kernel_launch(void* const* d_in, const int* in_sizes, int n_in,
                              void* d_out, int out_size, void* d_ws, size_t ws_size,
                              hipStream_t stream)
{
    const float4* xr    = (const float4*)d_in[0];
    const float4* xi    = (const float4*)d_in[1];
    const float*  angle = (const float*)d_in[2];

    float* out  = (float*)d_out;
    float4* outr = (float4*)out;            // first N floats: real part
    float4* outi = (float4*)(out + NELEM);  // next  N floats: imag part

    const int block = 256;
    const int grid  = 2048;  // grid-stride; ~6 iters/thread over 3*2^20 units

    cr_gate_kernel<<<grid, block, 0, stream>>>(xr, xi, angle, outr, outi);
}

// Round 2
// 45.595 us; speedup vs baseline: 1.0041x; 1.0041x over previous
//
#include <hip/hip_runtime.h>

// CR gate, D=2, L=24, control=axis0, target=axis1.
// N = 2^24 amplitudes. R = 2^22 (size of the "rest" axis).
// out = stack([real, imag]) of U @ x, laid out as [N reals][N imags].
//
// control=0 half: identity copy.
// control=1 half: M1 = cos(a/2) I - i sin(a/2) X applied across target axis.
//
// Key trick: output is write-once/never-read, inputs (128 MiB) are re-read
// every graph replay. Non-temporal stores keep the output stream from
// evicting the inputs out of the 256 MiB Infinity Cache, so input reads hit
// LLC and only the write stream pays HBM cost.

#define NELEM   (1u << 24)   // N
#define R4      (1u << 20)   // R / 4 (float4 units), R = N/4
#define COPY4   (1u << 21)   // (N/2)/4 float4 units in the copy half
#define TOTAL4  (COPY4 + R4) // total float4 work units

typedef float f32x4 __attribute__((ext_vector_type(4)));

__global__ __launch_bounds__(256) void cr_gate_kernel(
    const f32x4* __restrict__ xr,
    const f32x4* __restrict__ xi,
    const float* __restrict__ angle,
    f32x4* __restrict__ outr,
    f32x4* __restrict__ outi)
{
    const float half_a = 0.5f * angle[0];
    float s, c;
    sincosf(half_a, &s, &c);

    const unsigned stride = gridDim.x * blockDim.x;
    for (unsigned i = blockIdx.x * blockDim.x + threadIdx.x; i < TOTAL4; i += stride) {
        if (i < COPY4) {
            // control = 0: identity. Elements [0, N/2) of both arrays.
            __builtin_nontemporal_store(xr[i], &outr[i]);
            __builtin_nontemporal_store(xi[i], &outi[i]);
        } else {
            // control = 1: rotate target pair (t=0 at 2R + r, t=1 at 3R + r).
            const unsigned j  = i - COPY4;       // r / 4
            const unsigned ia = 2u * R4 + j;     // (2R + r) / 4
            const unsigned ib = 3u * R4 + j;     // (3R + r) / 4

            f32x4 r0 = xr[ia];
            f32x4 i0 = xi[ia];
            f32x4 r1 = xr[ib];
            f32x4 i1 = xi[ib];

            // out0 = c*x0 - i s * x1 ; out1 = -i s * x0 + c*x1
            f32x4 or0 = c * r0 + s * i1;
            f32x4 oi0 = c * i0 - s * r1;
            f32x4 or1 = c * r1 + s * i0;
            f32x4 oi1 = c * i1 - s * r0;

            __builtin_nontemporal_store(or0, &outr[ia]);
            __builtin_nontemporal_store(oi0, &outi[ia]);
            __builtin_nontemporal_store(or1, &outr[ib]);
            __builtin_nontemporal_store(oi1, &outi[ib]);
        }
    }
}

extern "C" void kernel_launch(void* const* d_in, const int* in_sizes, int n_in,
                              void* d_out, int out_size, void* d_ws, size_t ws_size,
                              hipStream_t stream)
{
    const f32x4* xr    = (const f32x4*)d_in[0];
    const f32x4* xi    = (const f32x4*)d_in[1];
    const float* angle = (const float*)d_in[2];

    float* out   = (float*)d_out;
    f32x4* outr  = (f32x4*)out;            // first N floats: real part
    f32x4* outi  = (f32x4*)(out + NELEM);  // next  N floats: imag part

    const int block = 256;
    const int grid  = 2048;  // 8 blocks/CU * 256 CU; exactly 6 grid-stride iters/thread

    cr_gate_kernel<<<grid, block, 0, stream>>>(xr, xi, angle, outr, outi);
}